// Round 2
// baseline (369.858 us; speedup 1.0000x reference)
//
#include <hip/hip_runtime.h>
#include <hip/hip_bf16.h>

// Problem constants (fixed by reference)
#define Bq 4
#define Tq 2048
#define Cq 1024
#define Hq 16
#define Dq 64
#define Mq (Bq*Tq)     // 8192 rows
#define N3q (3*Cq)     // 3072

typedef __attribute__((ext_vector_type(8))) short   short8;
typedef __attribute__((ext_vector_type(4))) float   f32x4;
typedef __attribute__((ext_vector_type(4))) unsigned short ushort4v;
typedef unsigned short u16;

__device__ __forceinline__ void gld_lds16(const u16* g, u16* l) {
  __builtin_amdgcn_global_load_lds(
      (const __attribute__((address_space(1))) unsigned int*)g,
      (__attribute__((address_space(3))) unsigned int*)l, 16, 0, 0);
}

__device__ __forceinline__ u16 f2bf(float f) {
  return __builtin_bit_cast(u16, __float2bfloat16(f));
}

__device__ __forceinline__ f32x4 mfma16(short8 a, short8 b, f32x4 c) {
  return __builtin_amdgcn_mfma_f32_16x16x32_bf16(a, b, c, 0, 0, 0);
}

// ---------------------------------------------------------------------------
// f32 -> bf16 convert (vectorized)
__global__ void cvt_bf16(const float* __restrict__ in, u16* __restrict__ out, int n) {
  int i = (blockIdx.x * 256 + threadIdx.x) * 4;
  if (i < n) {
    float4 v = *(const float4*)(in + i);
    ushort4v o;
    o.x = f2bf(v.x); o.y = f2bf(v.y); o.z = f2bf(v.z); o.w = f2bf(v.w);
    *(ushort4v*)(out + i) = o;
  }
}

// f32 [R][C] -> bf16 [C][R] tiled transpose (coalesced both sides)
__global__ void transpose_cvt(const float* __restrict__ in, u16* __restrict__ out,
                              int R, int C) {
  __shared__ float tile[32][33];
  int j0 = blockIdx.x * 32;   // col tile of input
  int i0 = blockIdx.y * 32;   // row tile of input
  int c = threadIdx.x & 31, r0 = threadIdx.x >> 5;  // 8 rows per pass
#pragma unroll
  for (int rr = 0; rr < 32; rr += 8)
    tile[r0 + rr][c] = in[(size_t)(i0 + r0 + rr) * C + j0 + c];
  __syncthreads();
#pragma unroll
  for (int rr = 0; rr < 32; rr += 8) {
    int j = r0 + rr;
    out[(size_t)(j0 + j) * R + i0 + c] = f2bf(tile[c][j]);
  }
}

// ---------------------------------------------------------------------------
// bf16 GEMM: D[M][N] = A[M][K] * Bt[N][K]^T + bias.  128x128 tile, BK=64,
// 4 waves (2x2), each wave 64x64 = 4x4 MFMA 16x16x32 tiles.
template<int OUT_BF16>
__global__ __launch_bounds__(256, 2) void gemm_bt(
    const u16* __restrict__ A, const u16* __restrict__ Bt,
    const float* __restrict__ bias, void* __restrict__ Dp,
    int M, int N, int K)
{
  __shared__ __align__(16) u16 lA[128 * 64];
  __shared__ __align__(16) u16 lB[128 * 64];
  const int t = threadIdx.x;
  const int l = t & 63, w = t >> 6;
  const int bn = blockIdx.x, bm = blockIdx.y;
  const int wr = (w >> 1) * 64, wc = (w & 1) * 64;

  const int srow = t >> 3;
  const int scol = 8 * ((t & 7) ^ (srow & 7));
  const u16* ga = A  + (size_t)(bm * 128 + srow) * K + scol;
  const u16* gb = Bt + (size_t)(bn * 128 + srow) * K + scol;

  f32x4 acc[4][4] = {};

  for (int k0 = 0; k0 < K; k0 += 64) {
    __syncthreads();
#pragma unroll
    for (int c = 0; c < 4; ++c) {
      gld_lds16(ga + (size_t)(32 * c) * K + k0, &lA[c * 2048 + w * 512]);
      gld_lds16(gb + (size_t)(32 * c) * K + k0, &lB[c * 2048 + w * 512]);
    }
    __syncthreads();

    short8 af[4][2], bf[4][2];
#pragma unroll
    for (int m = 0; m < 4; ++m)
#pragma unroll
      for (int kk = 0; kk < 2; ++kk) {
        int ar = wr + m * 16 + (l & 15);
        int slot = (kk * 4 + (l >> 4)) ^ (l & 7);
        af[m][kk] = *(const short8*)&lA[ar * 64 + slot * 8];
        int br = wc + m * 16 + (l & 15);
        bf[m][kk] = *(const short8*)&lB[br * 64 + slot * 8];
      }
#pragma unroll
    for (int kk = 0; kk < 2; ++kk)
#pragma unroll
      for (int m = 0; m < 4; ++m)
#pragma unroll
        for (int n = 0; n < 4; ++n)
          acc[m][n] = mfma16(af[m][kk], bf[n][kk], acc[m][n]);
  }

  float bv[4];
#pragma unroll
  for (int n = 0; n < 4; ++n) bv[n] = bias[bn * 128 + wc + n * 16 + (l & 15)];
#pragma unroll
  for (int m = 0; m < 4; ++m)
#pragma unroll
    for (int r = 0; r < 4; ++r) {
      int row = bm * 128 + wr + m * 16 + (l >> 4) * 4 + r;
      size_t base = (size_t)row * N + bn * 128 + wc + (l & 15);
#pragma unroll
      for (int n = 0; n < 4; ++n) {
        float v = acc[m][n][r] + bv[n];
        if (OUT_BF16) ((u16*)Dp)[base + n * 16] = f2bf(v);
        else          ((float*)Dp)[base + n * 16] = v;
      }
    }
}

// ---------------------------------------------------------------------------
// Causal flash attention, balanced + 2-phase pipelined.
// Block x in [0,16) handles q-strips {x, 31-x} (64 rows each) of head (b,h):
// every block does exactly 33 strip-iterations of compute.
// K double-buffered via global_load_lds (XOR slot swizzle); V reg-staged
// (lane=key scatter) into XOR-swizzled Vt[d][key]; P through XOR-swizzled Pl.
// LDS = 2*8 + 2*8 + 8 = 40KB -> 4 blocks/CU; grid 1024 = exactly 4/CU.
__global__ __launch_bounds__(256, 4) void flash_attn(
    const u16* __restrict__ qkv, u16* __restrict__ Y)
{
  __shared__ __align__(16) u16 Kl[2][64 * 64];
  __shared__ __align__(16) u16 Vt[2][64 * 64];   // [d][key], slot ^= d&7
  __shared__ __align__(16) u16 Pl[64 * 64];      // per-wave rows, slot ^= row&7

  const int t = threadIdx.x, l = t & 63, w = t >> 6;
  const int x  = blockIdx.x;            // 0..15
  const int bh = blockIdx.y;            // 0..63
  const int b  = bh >> 4, h = bh & 15;
  const int qA = x, qB = 31 - x;        // strip indices; jmax = qB
  const int jmax = qB;

  // Q fragments (A-role): rows q*64 + w*16 + (l&15), k = kk*32 + (l>>4)*8 + i
  short8 qfA[2], qfB[2];
  {
    const u16* qp = qkv + (size_t)(b * Tq + qA * 64 + w * 16 + (l & 15)) * N3q + h * 64;
    qfA[0] = *(const short8*)(qp + ((l >> 4) * 8));
    qfA[1] = *(const short8*)(qp + 32 + ((l >> 4) * 8));
    const u16* qp2 = qkv + (size_t)(b * Tq + qB * 64 + w * 16 + (l & 15)) * N3q + h * 64;
    qfB[0] = *(const short8*)(qp2 + ((l >> 4) * 8));
    qfB[1] = *(const short8*)(qp2 + 32 + ((l >> 4) * 8));
  }

  float mA[4], lsA[4], mB[4], lsB[4];
  f32x4 oA[4] = {}, oB[4] = {};
#pragma unroll
  for (int r = 0; r < 4; ++r) { mA[r] = -1e30f; lsA[r] = 0.f; mB[r] = -1e30f; lsB[r] = 0.f; }

  // K staging: thread t -> row c*32 + (t>>3), pre-swizzled source col
  const int ksrow = t >> 3;
  const int kscol = 8 * ((t & 7) ^ (ksrow & 7));
  // V staging: idx = t + 256c -> key = idx&63, dblock = idx>>6
  const int vkey = t & 63;

  // --- prologue: stage j=0 ---
  {
    const size_t krow0 = (size_t)(b * Tq);
#pragma unroll
    for (int c = 0; c < 2; ++c)
      gld_lds16(qkv + (krow0 + c * 32 + ksrow) * N3q + Cq + h * 64 + kscol,
                &Kl[0][c * 2048 + w * 512]);
    short8 vr[2];
#pragma unroll
    for (int c = 0; c < 2; ++c) {
      int dj = (t + 256 * c) >> 6;
      vr[c] = *(const short8*)(qkv + (krow0 + vkey) * N3q + 2 * Cq + h * 64 + dj * 8);
    }
    asm volatile("s_waitcnt vmcnt(0)" ::: "memory");
#pragma unroll
    for (int c = 0; c < 2; ++c) {
      int dj = (t + 256 * c) >> 6;
#pragma unroll
      for (int i = 0; i < 8; ++i)
        Vt[0][(dj * 8 + i) * 64 + (((vkey >> 3) ^ i) * 8) + (vkey & 7)] = (u16)vr[c][i];
    }
  }
  __syncthreads();

  int cur = 0;
  for (int j = 0; j <= jmax; ++j) {
    // --- issue next-tile staging (async) ---
    short8 vrn[2];
    if (j < jmax) {
      const size_t krow1 = (size_t)(b * Tq + (j + 1) * 64);
#pragma unroll
      for (int c = 0; c < 2; ++c)
        gld_lds16(qkv + (krow1 + c * 32 + ksrow) * N3q + Cq + h * 64 + kscol,
                  &Kl[cur ^ 1][c * 2048 + w * 512]);
#pragma unroll
      for (int c = 0; c < 2; ++c) {
        int dj = (t + 256 * c) >> 6;
        vrn[c] = *(const short8*)(qkv + (krow1 + vkey) * N3q + 2 * Cq + h * 64 + dj * 8);
      }
    }

    // --- compute both strips from buf[cur] ---
#pragma unroll
    for (int strip = 0; strip < 2; ++strip) {
      const short8* qf = strip ? qfB : qfA;
      float* m  = strip ? mB : mA;
      float* ls = strip ? lsB : lsA;
      f32x4* oacc = strip ? oB : oA;
      const int qb = strip ? qB : qA;
      if (!strip && j > qA) continue;   // strip A done (wave-uniform)

      // S = Q K^T
      f32x4 s[4] = {};
#pragma unroll
      for (int kk = 0; kk < 2; ++kk)
#pragma unroll
        for (int n = 0; n < 4; ++n) {
          int key = n * 16 + (l & 15);
          int slot = (kk * 4 + (l >> 4)) ^ (key & 7);
          short8 kf = *(const short8*)&Kl[cur][key * 64 + slot * 8];
          s[n] = mfma16(qf[kk], kf, s[n]);
        }

      if (j == qb) {  // diagonal block: causal mask
#pragma unroll
        for (int n = 0; n < 4; ++n) {
          int key = n * 16 + (l & 15);
#pragma unroll
          for (int r = 0; r < 4; ++r) {
            int q = w * 16 + (l >> 4) * 4 + r;
            if (key > q) s[n][r] = -1e30f;
          }
        }
      }

      // online softmax (scale 1/8 folded into exp args)
#pragma unroll
      for (int r = 0; r < 4; ++r) {
        float mx = fmaxf(fmaxf(s[0][r], s[1][r]), fmaxf(s[2][r], s[3][r]));
        mx = fmaxf(mx, __shfl_xor(mx, 1));
        mx = fmaxf(mx, __shfl_xor(mx, 2));
        mx = fmaxf(mx, __shfl_xor(mx, 4));
        mx = fmaxf(mx, __shfl_xor(mx, 8));
        float mn = fmaxf(m[r], mx);
        float fac = __expf((m[r] - mn) * 0.125f);
        float rs = 0.f;
#pragma unroll
        for (int n = 0; n < 4; ++n) {
          float p = __expf((s[n][r] - mn) * 0.125f);
          s[n][r] = p;
          rs += p;
        }
        rs += __shfl_xor(rs, 1);
        rs += __shfl_xor(rs, 2);
        rs += __shfl_xor(rs, 4);
        rs += __shfl_xor(rs, 8);
        ls[r] = ls[r] * fac + rs;
        m[r] = mn;
#pragma unroll
        for (int dn = 0; dn < 4; ++dn) oacc[dn][r] *= fac;
      }

      // P (C-layout) -> Pl (XOR slot) -> A-fragment
#pragma unroll
      for (int n = 0; n < 4; ++n)
#pragma unroll
        for (int r = 0; r < 4; ++r) {
          int row = w * 16 + (l >> 4) * 4 + r;
          int col = n * 16 + (l & 15);
          Pl[row * 64 + (((col >> 3) ^ (row & 7)) * 8) + (col & 7)] = f2bf(s[n][r]);
        }

      // O += P V
#pragma unroll
      for (int kk = 0; kk < 2; ++kk) {
        int slot = (kk * 4 + (l >> 4)) ^ (l & 7);
        short8 pf = *(const short8*)&Pl[(w * 16 + (l & 15)) * 64 + slot * 8];
#pragma unroll
        for (int dn = 0; dn < 4; ++dn) {
          int d = dn * 16 + (l & 15);
          short8 vf = *(const short8*)&Vt[cur][d * 64 + slot * 8];
          oacc[dn] = mfma16(pf, vf, oacc[dn]);
        }
      }
    }

    // --- drain staging, write V(j+1), single barrier ---
    if (j < jmax) {
      asm volatile("s_waitcnt vmcnt(0)" ::: "memory");
#pragma unroll
      for (int c = 0; c < 2; ++c) {
        int dj = (t + 256 * c) >> 6;
#pragma unroll
        for (int i = 0; i < 8; ++i)
          Vt[cur ^ 1][(dj * 8 + i) * 64 + (((vkey >> 3) ^ i) * 8) + (vkey & 7)] = (u16)vrn[c][i];
      }
    }
    __syncthreads();
    cur ^= 1;
  }

  // epilogue: normalize + store bf16, both strips
#pragma unroll
  for (int strip = 0; strip < 2; ++strip) {
    const int qb = strip ? qB : qA;
    float* ls = strip ? lsB : lsA;
    f32x4* oacc = strip ? oB : oA;
#pragma unroll
    for (int r = 0; r < 4; ++r) {
      float inv = 1.f / ls[r];
      size_t row = (size_t)(b * Tq + qb * 64 + w * 16 + (l >> 4) * 4 + r);
      u16* yp = Y + row * Cq + h * 64 + (l & 15);
#pragma unroll
      for (int dn = 0; dn < 4; ++dn)
        yp[dn * 16] = f2bf(oacc[dn][r] * inv);
    }
  }
}

// ---------------------------------------------------------------------------
extern "C" void kernel_launch(void* const* d_in, const int* in_sizes, int n_in,
                              void* d_out, int out_size, void* d_ws, size_t ws_size,
                              hipStream_t stream)
{
  const float* x      = (const float*)d_in[0];
  // d_in[1] = mask: exactly causal tril -> hardcoded, not read
  const float* W_attn = (const float*)d_in[2];
  const float* b_attn = (const float*)d_in[3];
  const float* W_proj = (const float*)d_in[4];
  const float* b_proj = (const float*)d_in[5];

  char* ws = (char*)d_ws;
  u16* x_bf    = (u16*)ws; ws += (size_t)Mq * Cq * 2;    // 16 MB
  u16* wqkv_t  = (u16*)ws; ws += (size_t)N3q * Cq * 2;   // 6 MB
  u16* wproj_t = (u16*)ws; ws += (size_t)Cq * Cq * 2;    // 2 MB
  u16* qkv     = (u16*)ws; ws += (size_t)Mq * N3q * 2;   // 48 MB
  u16* y       = (u16*)ws; ws += (size_t)Mq * Cq * 2;    // 16 MB
  if ((size_t)(ws - (char*)d_ws) > ws_size) return;      // ws too small: fail loud

  cvt_bf16<<<(Mq * Cq / 4 + 255) / 256, 256, 0, stream>>>(x, x_bf, Mq * Cq);
  transpose_cvt<<<dim3(N3q / 32, Cq / 32), 256, 0, stream>>>(W_attn, wqkv_t, Cq, N3q);
  transpose_cvt<<<dim3(Cq / 32, Cq / 32), 256, 0, stream>>>(W_proj, wproj_t, Cq, Cq);

  gemm_bt<1><<<dim3(N3q / 128, Mq / 128), 256, 0, stream>>>(
      x_bf, wqkv_t, b_attn, (void*)qkv, Mq, N3q, Cq);

  flash_attn<<<dim3(16, Bq * Hq), 256, 0, stream>>>(qkv, y);

  gemm_bt<0><<<dim3(Cq / 128, Mq / 128), 256, 0, stream>>>(
      y, wproj_t, b_proj, d_out, Mq, Cq, Cq);
}

// Round 3
// 318.582 us; speedup vs baseline: 1.1610x; 1.1610x over previous
//
#include <hip/hip_runtime.h>
#include <hip/hip_bf16.h>

// Problem constants (fixed by reference)
#define Bq 4
#define Tq 2048
#define Cq 1024
#define Hq 16
#define Dq 64
#define Mq (Bq*Tq)     // 8192 rows
#define N3q (3*Cq)     // 3072

typedef __attribute__((ext_vector_type(8))) short   short8;
typedef __attribute__((ext_vector_type(4))) float   f32x4;
typedef __attribute__((ext_vector_type(4))) unsigned short ushort4v;
typedef unsigned short u16;

__device__ __forceinline__ void gld_lds16(const u16* g, u16* l) {
  __builtin_amdgcn_global_load_lds(
      (const __attribute__((address_space(1))) unsigned int*)g,
      (__attribute__((address_space(3))) unsigned int*)l, 16, 0, 0);
}

__device__ __forceinline__ u16 f2bf(float f) {
  return __builtin_bit_cast(u16, __float2bfloat16(f));
}

__device__ __forceinline__ f32x4 mfma16(short8 a, short8 b, f32x4 c) {
  return __builtin_amdgcn_mfma_f32_16x16x32_bf16(a, b, c, 0, 0, 0);
}

// ---------------------------------------------------------------------------
// f32 -> bf16 convert (vectorized)
__global__ void cvt_bf16(const float* __restrict__ in, u16* __restrict__ out, int n) {
  int i = (blockIdx.x * 256 + threadIdx.x) * 4;
  if (i < n) {
    float4 v = *(const float4*)(in + i);
    ushort4v o;
    o.x = f2bf(v.x); o.y = f2bf(v.y); o.z = f2bf(v.z); o.w = f2bf(v.w);
    *(ushort4v*)(out + i) = o;
  }
}

// f32 [R][C] -> bf16 [C][R] tiled transpose (coalesced both sides)
__global__ void transpose_cvt(const float* __restrict__ in, u16* __restrict__ out,
                              int R, int C) {
  __shared__ float tile[32][33];
  int j0 = blockIdx.x * 32;   // col tile of input
  int i0 = blockIdx.y * 32;   // row tile of input
  int c = threadIdx.x & 31, r0 = threadIdx.x >> 5;  // 8 rows per pass
#pragma unroll
  for (int rr = 0; rr < 32; rr += 8)
    tile[r0 + rr][c] = in[(size_t)(i0 + r0 + rr) * C + j0 + c];
  __syncthreads();
#pragma unroll
  for (int rr = 0; rr < 32; rr += 8) {
    int j = r0 + rr;
    out[(size_t)(j0 + j) * R + i0 + c] = f2bf(tile[c][j]);
  }
}

// ---------------------------------------------------------------------------
// bf16 GEMM: D[M][N] = A[M][K] * Bt[N][K]^T + bias.  128x128 tile, BK=64,
// 4 waves (2x2), each wave 64x64 = 4x4 MFMA 16x16x32 tiles.
template<int OUT_BF16>
__global__ __launch_bounds__(256, 2) void gemm_bt(
    const u16* __restrict__ A, const u16* __restrict__ Bt,
    const float* __restrict__ bias, void* __restrict__ Dp,
    int M, int N, int K)
{
  __shared__ __align__(16) u16 lA[128 * 64];
  __shared__ __align__(16) u16 lB[128 * 64];
  const int t = threadIdx.x;
  const int l = t & 63, w = t >> 6;
  const int bn = blockIdx.x, bm = blockIdx.y;
  const int wr = (w >> 1) * 64, wc = (w & 1) * 64;

  const int srow = t >> 3;
  const int scol = 8 * ((t & 7) ^ (srow & 7));
  const u16* ga = A  + (size_t)(bm * 128 + srow) * K + scol;
  const u16* gb = Bt + (size_t)(bn * 128 + srow) * K + scol;

  f32x4 acc[4][4] = {};

  for (int k0 = 0; k0 < K; k0 += 64) {
    __syncthreads();
#pragma unroll
    for (int c = 0; c < 4; ++c) {
      gld_lds16(ga + (size_t)(32 * c) * K + k0, &lA[c * 2048 + w * 512]);
      gld_lds16(gb + (size_t)(32 * c) * K + k0, &lB[c * 2048 + w * 512]);
    }
    __syncthreads();

    short8 af[4][2], bf[4][2];
#pragma unroll
    for (int m = 0; m < 4; ++m)
#pragma unroll
      for (int kk = 0; kk < 2; ++kk) {
        int ar = wr + m * 16 + (l & 15);
        int slot = (kk * 4 + (l >> 4)) ^ (l & 7);
        af[m][kk] = *(const short8*)&lA[ar * 64 + slot * 8];
        int br = wc + m * 16 + (l & 15);
        bf[m][kk] = *(const short8*)&lB[br * 64 + slot * 8];
      }
#pragma unroll
    for (int kk = 0; kk < 2; ++kk)
#pragma unroll
      for (int m = 0; m < 4; ++m)
#pragma unroll
        for (int n = 0; n < 4; ++n)
          acc[m][n] = mfma16(af[m][kk], bf[n][kk], acc[m][n]);
  }

  float bv[4];
#pragma unroll
  for (int n = 0; n < 4; ++n) bv[n] = bias[bn * 128 + wc + n * 16 + (l & 15)];
#pragma unroll
  for (int m = 0; m < 4; ++m)
#pragma unroll
    for (int r = 0; r < 4; ++r) {
      int row = bm * 128 + wr + m * 16 + (l >> 4) * 4 + r;
      size_t base = (size_t)row * N + bn * 128 + wc + (l & 15);
#pragma unroll
      for (int n = 0; n < 4; ++n) {
        float v = acc[m][n][r] + bv[n];
        if (OUT_BF16) ((u16*)Dp)[base + n * 16] = f2bf(v);
        else          ((float*)Dp)[base + n * 16] = v;
      }
    }
}

// ---------------------------------------------------------------------------
// Causal flash attention, balanced + 2-phase pipelined + XCD-swizzled.
// Linear block id -> (xcd = id%8, x = (id>>3)&15, bh = xcd + 8*(id>>7)):
// all 16 strip-blocks of one (b,h) land on ONE XCD (K+V/head = 512KB < 4MB L2)
// and are co-resident (grid 1024 = 4 blocks/CU exactly), so K/V tile j is
// HBM-fetched once per head and L2-hit by the other 15 blocks.
// Block handles q-strips {x, 31-x}: every block does exactly 33 strip-iters.
__global__ __launch_bounds__(256, 4) void flash_attn(
    const u16* __restrict__ qkv, u16* __restrict__ Y)
{
  __shared__ __align__(16) u16 Kl[2][64 * 64];
  __shared__ __align__(16) u16 Vt[2][64 * 64];   // [d][key], slot ^= d&7
  __shared__ __align__(16) u16 Pl[64 * 64];      // per-wave rows, slot ^= row&7

  const int t = threadIdx.x, l = t & 63, w = t >> 6;
  // XCD-aware swizzle of the 1024 linear block ids
  const int id  = blockIdx.x + 16 * blockIdx.y;   // HW linear id, x fastest
  const int xcd = id & 7;
  const int s   = id >> 3;
  const int x   = s & 15;                          // strip pair 0..15
  const int bh  = xcd + 8 * (s >> 4);              // 0..63, 8 heads per XCD
  const int b  = bh >> 4, h = bh & 15;
  const int qA = x, qB = 31 - x;        // strip indices; jmax = qB
  const int jmax = qB;

  // Q fragments (A-role): rows q*64 + w*16 + (l&15), k = kk*32 + (l>>4)*8 + i
  short8 qfA[2], qfB[2];
  {
    const u16* qp = qkv + (size_t)(b * Tq + qA * 64 + w * 16 + (l & 15)) * N3q + h * 64;
    qfA[0] = *(const short8*)(qp + ((l >> 4) * 8));
    qfA[1] = *(const short8*)(qp + 32 + ((l >> 4) * 8));
    const u16* qp2 = qkv + (size_t)(b * Tq + qB * 64 + w * 16 + (l & 15)) * N3q + h * 64;
    qfB[0] = *(const short8*)(qp2 + ((l >> 4) * 8));
    qfB[1] = *(const short8*)(qp2 + 32 + ((l >> 4) * 8));
  }

  float mA[4], lsA[4], mB[4], lsB[4];
  f32x4 oA[4] = {}, oB[4] = {};
#pragma unroll
  for (int r = 0; r < 4; ++r) { mA[r] = -1e30f; lsA[r] = 0.f; mB[r] = -1e30f; lsB[r] = 0.f; }

  // K staging: thread t -> row c*32 + (t>>3), pre-swizzled source col
  const int ksrow = t >> 3;
  const int kscol = 8 * ((t & 7) ^ (ksrow & 7));
  // V staging: idx = t + 256c -> key = idx&63, dblock = idx>>6
  const int vkey = t & 63;

  // --- prologue: stage j=0 ---
  {
    const size_t krow0 = (size_t)(b * Tq);
#pragma unroll
    for (int c = 0; c < 2; ++c)
      gld_lds16(qkv + (krow0 + c * 32 + ksrow) * N3q + Cq + h * 64 + kscol,
                &Kl[0][c * 2048 + w * 512]);
    short8 vr[2];
#pragma unroll
    for (int c = 0; c < 2; ++c) {
      int dj = (t + 256 * c) >> 6;
      vr[c] = *(const short8*)(qkv + (krow0 + vkey) * N3q + 2 * Cq + h * 64 + dj * 8);
    }
    asm volatile("s_waitcnt vmcnt(0)" ::: "memory");
#pragma unroll
    for (int c = 0; c < 2; ++c) {
      int dj = (t + 256 * c) >> 6;
#pragma unroll
      for (int i = 0; i < 8; ++i)
        Vt[0][(dj * 8 + i) * 64 + (((vkey >> 3) ^ i) * 8) + (vkey & 7)] = (u16)vr[c][i];
    }
  }
  __syncthreads();

  int cur = 0;
  for (int j = 0; j <= jmax; ++j) {
    // --- issue next-tile staging (async) ---
    short8 vrn[2];
    if (j < jmax) {
      const size_t krow1 = (size_t)(b * Tq + (j + 1) * 64);
#pragma unroll
      for (int c = 0; c < 2; ++c)
        gld_lds16(qkv + (krow1 + c * 32 + ksrow) * N3q + Cq + h * 64 + kscol,
                  &Kl[cur ^ 1][c * 2048 + w * 512]);
#pragma unroll
      for (int c = 0; c < 2; ++c) {
        int dj = (t + 256 * c) >> 6;
        vrn[c] = *(const short8*)(qkv + (krow1 + vkey) * N3q + 2 * Cq + h * 64 + dj * 8);
      }
    }

    // --- compute both strips from buf[cur] ---
#pragma unroll
    for (int strip = 0; strip < 2; ++strip) {
      const short8* qf = strip ? qfB : qfA;
      float* m  = strip ? mB : mA;
      float* ls = strip ? lsB : lsA;
      f32x4* oacc = strip ? oB : oA;
      const int qb = strip ? qB : qA;
      if (!strip && j > qA) continue;   // strip A done (wave-uniform)

      // S = Q K^T
      f32x4 s4[4] = {};
#pragma unroll
      for (int kk = 0; kk < 2; ++kk)
#pragma unroll
        for (int n = 0; n < 4; ++n) {
          int key = n * 16 + (l & 15);
          int slot = (kk * 4 + (l >> 4)) ^ (key & 7);
          short8 kf = *(const short8*)&Kl[cur][key * 64 + slot * 8];
          s4[n] = mfma16(qf[kk], kf, s4[n]);
        }

      if (j == qb) {  // diagonal block: causal mask
#pragma unroll
        for (int n = 0; n < 4; ++n) {
          int key = n * 16 + (l & 15);
#pragma unroll
          for (int r = 0; r < 4; ++r) {
            int q = w * 16 + (l >> 4) * 4 + r;
            if (key > q) s4[n][r] = -1e30f;
          }
        }
      }

      // online softmax (scale 1/8 folded into exp args)
#pragma unroll
      for (int r = 0; r < 4; ++r) {
        float mx = fmaxf(fmaxf(s4[0][r], s4[1][r]), fmaxf(s4[2][r], s4[3][r]));
        mx = fmaxf(mx, __shfl_xor(mx, 1));
        mx = fmaxf(mx, __shfl_xor(mx, 2));
        mx = fmaxf(mx, __shfl_xor(mx, 4));
        mx = fmaxf(mx, __shfl_xor(mx, 8));
        float mn = fmaxf(m[r], mx);
        float fac = __expf((m[r] - mn) * 0.125f);
        float rs = 0.f;
#pragma unroll
        for (int n = 0; n < 4; ++n) {
          float p = __expf((s4[n][r] - mn) * 0.125f);
          s4[n][r] = p;
          rs += p;
        }
        rs += __shfl_xor(rs, 1);
        rs += __shfl_xor(rs, 2);
        rs += __shfl_xor(rs, 4);
        rs += __shfl_xor(rs, 8);
        ls[r] = ls[r] * fac + rs;
        m[r] = mn;
#pragma unroll
        for (int dn = 0; dn < 4; ++dn) oacc[dn][r] *= fac;
      }

      // P (C-layout) -> Pl (XOR slot) -> A-fragment
#pragma unroll
      for (int n = 0; n < 4; ++n)
#pragma unroll
        for (int r = 0; r < 4; ++r) {
          int row = w * 16 + (l >> 4) * 4 + r;
          int col = n * 16 + (l & 15);
          Pl[row * 64 + (((col >> 3) ^ (row & 7)) * 8) + (col & 7)] = f2bf(s4[n][r]);
        }

      // O += P V
#pragma unroll
      for (int kk = 0; kk < 2; ++kk) {
        int slot = (kk * 4 + (l >> 4)) ^ (l & 7);
        short8 pf = *(const short8*)&Pl[(w * 16 + (l & 15)) * 64 + slot * 8];
#pragma unroll
        for (int dn = 0; dn < 4; ++dn) {
          int d = dn * 16 + (l & 15);
          short8 vf = *(const short8*)&Vt[cur][d * 64 + slot * 8];
          oacc[dn] = mfma16(pf, vf, oacc[dn]);
        }
      }
    }

    // --- drain staging, write V(j+1), single barrier ---
    if (j < jmax) {
      asm volatile("s_waitcnt vmcnt(0)" ::: "memory");
#pragma unroll
      for (int c = 0; c < 2; ++c) {
        int dj = (t + 256 * c) >> 6;
#pragma unroll
        for (int i = 0; i < 8; ++i)
          Vt[cur ^ 1][(dj * 8 + i) * 64 + (((vkey >> 3) ^ i) * 8) + (vkey & 7)] = (u16)vrn[c][i];
      }
    }
    __syncthreads();
    cur ^= 1;
  }

  // epilogue: normalize + store bf16, both strips
#pragma unroll
  for (int strip = 0; strip < 2; ++strip) {
    const int qb = strip ? qB : qA;
    float* ls = strip ? lsB : lsA;
    f32x4* oacc = strip ? oB : oA;
#pragma unroll
    for (int r = 0; r < 4; ++r) {
      float inv = 1.f / ls[r];
      size_t row = (size_t)(b * Tq + qb * 64 + w * 16 + (l >> 4) * 4 + r);
      u16* yp = Y + row * Cq + h * 64 + (l & 15);
#pragma unroll
      for (int dn = 0; dn < 4; ++dn)
        yp[dn * 16] = f2bf(oacc[dn][r] * inv);
    }
  }
}

// ---------------------------------------------------------------------------
extern "C" void kernel_launch(void* const* d_in, const int* in_sizes, int n_in,
                              void* d_out, int out_size, void* d_ws, size_t ws_size,
                              hipStream_t stream)
{
  const float* x      = (const float*)d_in[0];
  // d_in[1] = mask: exactly causal tril -> hardcoded, not read
  const float* W_attn = (const float*)d_in[2];
  const float* b_attn = (const float*)d_in[3];
  const float* W_proj = (const float*)d_in[4];
  const float* b_proj = (const float*)d_in[5];

  char* ws = (char*)d_ws;
  u16* x_bf    = (u16*)ws; ws += (size_t)Mq * Cq * 2;    // 16 MB
  u16* wqkv_t  = (u16*)ws; ws += (size_t)N3q * Cq * 2;   // 6 MB
  u16* wproj_t = (u16*)ws; ws += (size_t)Cq * Cq * 2;    // 2 MB
  u16* qkv     = (u16*)ws; ws += (size_t)Mq * N3q * 2;   // 48 MB
  u16* y       = (u16*)ws; ws += (size_t)Mq * Cq * 2;    // 16 MB
  if ((size_t)(ws - (char*)d_ws) > ws_size) return;      // ws too small: fail loud

  cvt_bf16<<<(Mq * Cq / 4 + 255) / 256, 256, 0, stream>>>(x, x_bf, Mq * Cq);
  transpose_cvt<<<dim3(N3q / 32, Cq / 32), 256, 0, stream>>>(W_attn, wqkv_t, Cq, N3q);
  transpose_cvt<<<dim3(Cq / 32, Cq / 32), 256, 0, stream>>>(W_proj, wproj_t, Cq, Cq);

  gemm_bt<1><<<dim3(N3q / 128, Mq / 128), 256, 0, stream>>>(
      x_bf, wqkv_t, b_attn, (void*)qkv, Mq, N3q, Cq);

  flash_attn<<<dim3(16, Bq * Hq), 256, 0, stream>>>(qkv, y);

  gemm_bt<0><<<dim3(Cq / 128, Mq / 128), 256, 0, stream>>>(
      y, wproj_t, b_proj, d_out, Mq, Cq, Cq);
}